// Round 10
// baseline (230.819 us; speedup 1.0000x reference)
//
#include <hip/hip_runtime.h>
#include <hip/hip_bf16.h>
#include <hip/hip_fp16.h>
#include <math.h>

#define BB 4
#define CC 64
#define OO 64
#define HH 96
#define WW 320
#define HWP (HH*WW)   // 30720
#define NPIX (BB*HWP) // 122880

typedef __attribute__((ext_vector_type(8))) short bf16x8;
typedef __attribute__((ext_vector_type(8))) unsigned short u16x8;
typedef __attribute__((ext_vector_type(4))) float f32x4;

__device__ inline unsigned short f2bf(float f) {
    unsigned int u = __float_as_uint(f);
    u = (u + 0x7FFFu + ((u >> 16) & 1u)) >> 16;
    return (unsigned short)u;
}
__device__ inline float bf2f(unsigned short s) {
    return __uint_as_float(((unsigned int)s) << 16);
}
// pack two interp results as adjacent bf16 (truncating): 3 VALU ops
__device__ inline unsigned int pack2bf(float lo, float hi) {
    return (__float_as_uint(lo) >> 16) | (__float_as_uint(hi) & 0xffff0000u);
}
__device__ inline unsigned short f2h(float f) { return __half_as_ushort(__float2half(f)); }
__device__ inline float h2f(unsigned short u) { return __half2float(__ushort_as_half(u)); }

// ---------------------------------------------------------------------------
// K_prep: all bf16 weight repacks in one launch.  [R8-verified]
// ---------------------------------------------------------------------------
#define PREP_N (36864 + 27648 + 1024 + 9216 + 1024)
__global__ void k_prep(const float* __restrict__ cw,
                       const float* __restrict__ lw1, const float* __restrict__ mw,
                       const float* __restrict__ lw2,
                       const float* __restrict__ fw1, const float* __restrict__ fw2,
                       unsigned short* __restrict__ cwT,
                       unsigned short* __restrict__ Wlm,
                       unsigned short* __restrict__ lw2T,
                       unsigned short* __restrict__ Wf,
                       unsigned short* __restrict__ fw2A) {
    int e = blockIdx.x * 256 + threadIdx.x;
    if (e < 36864) {
        int k = e >> 12, r = e & 4095, o = r >> 6, ci = r & 63;
        cwT[e] = f2bf(cw[o * 576 + ci * 9 + k]);
        return;
    }
    e -= 36864;
    if (e < 27648) {
        int k = e / 3072, r = e % 3072, row = r >> 6, ci = r & 63;
        float v = 0.f;
        if (row < 32) v = lw1[row * 576 + ci * 9 + k];
        else if (row < 41) v = mw[(row - 32) * 576 + ci * 9 + k];
        Wlm[e] = f2bf(v);
        return;
    }
    e -= 27648;
    if (e < 1024) { lw2T[e] = f2bf(lw2[e]); return; }
    e -= 1024;
    if (e < 9216) {
        int k = e >> 10, r = e & 1023, o = r >> 5, cl = r & 31;
        Wf[e] = f2bf(fw1[o * 576 + (32 + cl) * 9 + k]);
        return;
    }
    e -= 9216;
    if (e < 1024) {
        int m = e >> 5, ci = e & 31;
        fw2A[e] = f2bf(m < 18 ? fw2[m * 32 + ci] : 0.f);
    }
}

// ---------------------------------------------------------------------------
// K1: global MLP -> Gsum.  [R8-verified]
// ---------------------------------------------------------------------------
__global__ void k_glob(const float* __restrict__ sb,
                       const float* __restrict__ gw1, const float* __restrict__ gb1,
                       const float* __restrict__ gw2, const float* __restrict__ gb2,
                       const float* __restrict__ fw1,
                       float* __restrict__ gsum) {
    __shared__ float g_s[BB * 32];
    int tid = threadIdx.x;  // 128 threads
    if (tid < 128) {
        int b = tid >> 5, i = tid & 31;
        float b0 = sb[b * 5 + 4] - sb[b * 5 + 2];
        float b1 = sb[b * 5 + 3] - sb[b * 5 + 1];
        float acc = gb2[i];
        for (int j = 0; j < 64; ++j) {
            float h1 = b0 * gw1[j * 2 + 0] + b1 * gw1[j * 2 + 1] + gb1[j];
            h1 = fmaxf(h1, 0.f);
            acc += gw2[i * 64 + j] * h1;
        }
        g_s[b * 32 + i] = acc;
    }
    __syncthreads();
    for (int e = tid; e < BB * 32 * 9; e += blockDim.x) {
        int b = e / 288, r = e % 288, o = r / 9, k = r % 9;
        float s = 0.f;
        for (int ci = 0; ci < 32; ++ci)
            s += g_s[b * 32 + ci] * fw1[o * 576 + ci * 9 + k];
        gsum[e] = s;
    }
}

// ---------------------------------------------------------------------------
// K_xT: NCHW f32 -> NHWC bf16.  [R8-verified]
// ---------------------------------------------------------------------------
__global__ __launch_bounds__(256) void k_xT(const float* __restrict__ x,
                                            unsigned short* __restrict__ xT) {
    __shared__ unsigned short Ls[64 * 66];
    int tid = threadIdx.x;
    int p0 = blockIdx.x * 64;
    int b = p0 / HWP;
    int rem0 = p0 % HWP;
    int px = tid & 63;
    int g4 = tid >> 6;   // 0..3
    const float* xb = x + (size_t)b * CC * HWP + rem0;
#pragma unroll
    for (int it = 0; it < 16; ++it) {
        int ci = it * 4 + g4;
        Ls[px * 66 + ci] = f2bf(xb[(size_t)ci * HWP + px]);
    }
    __syncthreads();
#pragma unroll
    for (int it = 0; it < 16; ++it) {
        int p = it * 4 + g4;
        xT[(size_t)(p0 + p) * 64 + px] = Ls[p * 66 + px];
    }
}

// ---------------------------------------------------------------------------
// K2: loc+mask MFMA implicit GEMM.  [R8-verified]
// ---------------------------------------------------------------------------
__global__ __launch_bounds__(256) void k_locmask(
        const unsigned short* __restrict__ xT,
        const unsigned short* __restrict__ Wlm,
        const unsigned short* __restrict__ lw2T,
        const float* __restrict__ lb1, const float* __restrict__ lb2,
        const float* __restrict__ mb,
        unsigned short* __restrict__ lT, unsigned short* __restrict__ mbuf) {
    __shared__ unsigned short Vs[128 * 72];
    __shared__ unsigned short Ws[48 * 72];
    __shared__ unsigned short VsL[128 * 40];
    __shared__ unsigned short W2[32 * 40];

    int tid = threadIdx.x;
    int p0 = blockIdx.x * 128;
    int rem0 = p0 % HWP;

    int lane = tid & 63, wv = tid >> 6;
    int lr = lane & 15, lq = lane >> 4;
    int n0 = wv * 32;

    int spx = tid >> 1;      // staging pixel 0..127
    int shf = tid & 1;       // ci half
    int sy = (rem0 + spx) / WW;
    int sx = (rem0 + spx) % WW;

    f32x4 acc[3][2];
#pragma unroll
    for (int mt = 0; mt < 3; ++mt)
#pragma unroll
        for (int t = 0; t < 2; ++t) acc[mt][t] = (f32x4){0.f, 0.f, 0.f, 0.f};

    for (int k = 0; k < 9; ++k) {
        int dy = k / 3 - 1, dx = k % 3 - 1;
        __syncthreads();
        // stage A: 48 rows x 64 ci = 384 16B chunks
#pragma unroll
        for (int c = tid; c < 384; c += 256) {
            int row = c >> 3, g = c & 7;
            *(float4*)&Ws[row * 72 + g * 8] =
                *(const float4*)&Wlm[((size_t)k * 48 + row) * 64 + g * 8];
        }
        // stage B: this thread's (px, ci-half) = 4 x 16B
        {
            int yy = sy + dy, xw = sx + dx;
            bool valid = (yy >= 0) && (yy < HH) && (xw >= 0) && (xw < WW);
            unsigned short* dst = &Vs[spx * 72 + shf * 32];
            if (valid) {
                const unsigned short* src =
                    xT + ((size_t)(p0 + spx) + (dy * WW + dx)) * 64 + shf * 32;
#pragma unroll
                for (int j = 0; j < 4; ++j)
                    *(float4*)(dst + j * 8) = *(const float4*)(src + j * 8);
            } else {
                float4 z = {0.f, 0.f, 0.f, 0.f};
#pragma unroll
                for (int j = 0; j < 4; ++j) *(float4*)(dst + j * 8) = z;
            }
        }
        __syncthreads();
#pragma unroll
        for (int h = 0; h < 2; ++h) {
            bf16x8 b0 = *(const bf16x8*)&Vs[(n0 + lr) * 72 + h * 32 + lq * 8];
            bf16x8 b1 = *(const bf16x8*)&Vs[(n0 + 16 + lr) * 72 + h * 32 + lq * 8];
#pragma unroll
            for (int mt = 0; mt < 3; ++mt) {
                bf16x8 a = *(const bf16x8*)&Ws[(mt * 16 + lr) * 72 + h * 32 + lq * 8];
                acc[mt][0] = __builtin_amdgcn_mfma_f32_16x16x32_bf16(a, b0, acc[mt][0], 0, 0, 0);
                acc[mt][1] = __builtin_amdgcn_mfma_f32_16x16x32_bf16(a, b1, acc[mt][1], 0, 0, 0);
            }
        }
    }

    // stage lw2 A while finishing epilogue
#pragma unroll
    for (int c = tid; c < 128; c += 256) {
        int row = c >> 2, g = c & 3;
        *(float4*)&W2[row * 40 + g * 8] = *(const float4*)&lw2T[row * 32 + g * 8];
    }
    // loc1: bias + relu -> VsL[px][m] bf16
#pragma unroll
    for (int mt = 0; mt < 2; ++mt)
#pragma unroll
        for (int t = 0; t < 2; ++t)
#pragma unroll
            for (int r = 0; r < 4; ++r) {
                int m = mt * 16 + lq * 4 + r;
                float v = acc[mt][t][r] + lb1[m];
                VsL[(n0 + t * 16 + lr) * 40 + m] = f2bf(fmaxf(v, 0.f));
            }
    // mask rows (mt=2): sigmoid -> mbuf
#pragma unroll
    for (int t = 0; t < 2; ++t)
#pragma unroll
        for (int r = 0; r < 4; ++r) {
            int j = lq * 4 + r;
            if (j < 9) {
                float v = acc[2][t][r] + mb[j];
                v = 1.f / (1.f + __expf(-v));
                mbuf[(size_t)j * NPIX + p0 + n0 + t * 16 + lr] = f2bf(v);
            }
        }
    __syncthreads();
    // GEMM2: l = lw2 x relu(l1), K=32 (one MFMA step)
    f32x4 acc2[2][2];
#pragma unroll
    for (int mt = 0; mt < 2; ++mt)
#pragma unroll
        for (int t = 0; t < 2; ++t) acc2[mt][t] = (f32x4){0.f, 0.f, 0.f, 0.f};
#pragma unroll
    for (int t = 0; t < 2; ++t) {
        bf16x8 b2 = *(const bf16x8*)&VsL[(n0 + t * 16 + lr) * 40 + lq * 8];
#pragma unroll
        for (int mt = 0; mt < 2; ++mt) {
            bf16x8 a2 = *(const bf16x8*)&W2[(mt * 16 + lr) * 40 + lq * 8];
            acc2[mt][t] = __builtin_amdgcn_mfma_f32_16x16x32_bf16(a2, b2, acc2[mt][t], 0, 0, 0);
        }
    }
    __syncthreads();  // Vs reuse as [px][40] shuffle buffer
#pragma unroll
    for (int mt = 0; mt < 2; ++mt)
#pragma unroll
        for (int t = 0; t < 2; ++t)
#pragma unroll
            for (int r = 0; r < 4; ++r) {
                int m = mt * 16 + lq * 4 + r;
                Vs[(n0 + t * 16 + lr) * 40 + m] = f2bf(acc2[mt][t][r] + lb2[m]);
            }
    __syncthreads();
    // coalesced NHWC store of l
    {
        int px = tid >> 1, hf = tid & 1;
        float4 v0 = *(const float4*)&Vs[px * 40 + hf * 16];
        float4 v1 = *(const float4*)&Vs[px * 40 + hf * 16 + 8];
        unsigned short* dst = lT + (size_t)(p0 + px) * 32 + hf * 16;
        *(float4*)dst = v0;
        *(float4*)(dst + 8) = v1;
    }
}

// ---------------------------------------------------------------------------
// K3: fuse conv MFMA implicit GEMM -> ysA/xsA.  [R8-verified]
// ---------------------------------------------------------------------------
__global__ __launch_bounds__(256) void k_fuse(
        const unsigned short* __restrict__ lT,
        const float* __restrict__ gsum,
        const unsigned short* __restrict__ Wf,
        const unsigned short* __restrict__ fw2A,
        const float* __restrict__ fb1, const float* __restrict__ fb2,
        float* __restrict__ ysA, float* __restrict__ xsA) {
    __shared__ unsigned short Vs[128 * 40];
    __shared__ unsigned short Ws[32 * 40];
    __shared__ unsigned short VsF[128 * 40];
    __shared__ unsigned short W2[32 * 40];
    __shared__ float gs[288];

    int tid = threadIdx.x;
    int p0 = blockIdx.x * 128;
    int b = p0 / HWP;
    int rem0 = p0 % HWP;

    int lane = tid & 63, wv = tid >> 6;
    int lr = lane & 15, lq = lane >> 4;
    int n0 = wv * 32;

    int spx = tid >> 1;
    int shf = tid & 1;
    int sy = (rem0 + spx) / WW;
    int sx = (rem0 + spx) % WW;

    for (int e = tid; e < 288; e += 256) gs[e] = gsum[b * 288 + e];

    f32x4 acc[2][2];
#pragma unroll
    for (int mt = 0; mt < 2; ++mt)
#pragma unroll
        for (int t = 0; t < 2; ++t) acc[mt][t] = (f32x4){0.f, 0.f, 0.f, 0.f};

    for (int k = 0; k < 9; ++k) {
        int dy = k / 3 - 1, dx = k % 3 - 1;
        __syncthreads();
#pragma unroll
        for (int c = tid; c < 128; c += 256) {
            int row = c >> 2, g = c & 3;
            *(float4*)&Ws[row * 40 + g * 8] =
                *(const float4*)&Wf[((size_t)k * 32 + row) * 32 + g * 8];
        }
        {
            int yy = sy + dy, xw = sx + dx;
            bool valid = (yy >= 0) && (yy < HH) && (xw >= 0) && (xw < WW);
            unsigned short* dst = &Vs[spx * 40 + shf * 16];
            if (valid) {
                const unsigned short* src =
                    lT + ((size_t)(p0 + spx) + (dy * WW + dx)) * 32 + shf * 16;
                *(float4*)dst = *(const float4*)src;
                *(float4*)(dst + 8) = *(const float4*)(src + 8);
            } else {
                float4 z = {0.f, 0.f, 0.f, 0.f};
                *(float4*)dst = z;
                *(float4*)(dst + 8) = z;
            }
        }
        __syncthreads();
#pragma unroll
        for (int t = 0; t < 2; ++t) {
            bf16x8 bfr = *(const bf16x8*)&Vs[(n0 + t * 16 + lr) * 40 + lq * 8];
#pragma unroll
            for (int mt = 0; mt < 2; ++mt) {
                bf16x8 a = *(const bf16x8*)&Ws[(mt * 16 + lr) * 40 + lq * 8];
                acc[mt][t] = __builtin_amdgcn_mfma_f32_16x16x32_bf16(a, bfr, acc[mt][t], 0, 0, 0);
            }
        }
    }

#pragma unroll
    for (int c = tid; c < 128; c += 256) {
        int row = c >> 2, g = c & 3;
        *(float4*)&W2[row * 40 + g * 8] = *(const float4*)&fw2A[row * 32 + g * 8];
    }
    // epilogue: + fb1 + valid-tap Gsum, relu -> VsF
#pragma unroll
    for (int t = 0; t < 2; ++t) {
        int px = n0 + t * 16 + lr;
        int rem = rem0 + px;
        int y = rem / WW, xx = rem % WW;
        bool vk[9];
#pragma unroll
        for (int k = 0; k < 9; ++k) {
            int yy = y + k / 3 - 1, xw = xx + k % 3 - 1;
            vk[k] = (yy >= 0) && (yy < HH) && (xw >= 0) && (xw < WW);
        }
#pragma unroll
        for (int mt = 0; mt < 2; ++mt)
#pragma unroll
            for (int r = 0; r < 4; ++r) {
                int m = mt * 16 + lq * 4 + r;
                float s = fb1[m];
#pragma unroll
                for (int k = 0; k < 9; ++k)
                    if (vk[k]) s += gs[m * 9 + k];
                float v = acc[mt][t][r] + s;
                VsF[px * 40 + m] = f2bf(fmaxf(v, 0.f));
            }
    }
    __syncthreads();
    f32x4 acc3[2][2];
#pragma unroll
    for (int mt = 0; mt < 2; ++mt)
#pragma unroll
        for (int t = 0; t < 2; ++t) acc3[mt][t] = (f32x4){0.f, 0.f, 0.f, 0.f};
#pragma unroll
    for (int t = 0; t < 2; ++t) {
        bf16x8 b2 = *(const bf16x8*)&VsF[(n0 + t * 16 + lr) * 40 + lq * 8];
#pragma unroll
        for (int mt = 0; mt < 2; ++mt) {
            bf16x8 a2 = *(const bf16x8*)&W2[(mt * 16 + lr) * 40 + lq * 8];
            acc3[mt][t] = __builtin_amdgcn_mfma_f32_16x16x32_bf16(a2, b2, acc3[mt][t], 0, 0, 0);
        }
    }
#pragma unroll
    for (int t = 0; t < 2; ++t) {
        int px = n0 + t * 16 + lr;
        int p = p0 + px;
        int rem = rem0 + px;
        int y = rem / WW, xx = rem % WW;
#pragma unroll
        for (int mt = 0; mt < 2; ++mt)
#pragma unroll
            for (int r = 0; r < 4; ++r) {
                int m = mt * 16 + lq * 4 + r;
                if (m < 18) {
                    int k = m >> 1;
                    float v = acc3[mt][t][r] + fb2[m];
                    if ((m & 1) == 0)
                        ysA[(size_t)k * NPIX + p] = (float)(y + k / 3 - 1) + v;
                    else
                        xsA[(size_t)k * NPIX + p] = (float)(xx + k % 3 - 1) + v;
                }
            }
    }
}

// ---------------------------------------------------------------------------
// K4: deformable conv, MFMA implicit GEMM (R9-verified structure).
// DELTA R10: cfA stored as fp16x4 (ushort4, 8B) and igA as int2
// (base corner + packed {dy,dx} deltas, 8B) instead of float4+int4 —
// LDS 36864 -> 27648 B => 4 -> 5 blocks/CU. Same barriers, same mappings.
// ---------------------------------------------------------------------------
__global__ __launch_bounds__(256) void k_deform(
        const unsigned short* __restrict__ xT,
        const unsigned short* __restrict__ cwT, const float* __restrict__ cb,
        const float* __restrict__ ysA, const float* __restrict__ xsA,
        const unsigned short* __restrict__ mA, float* __restrict__ out) {
    __shared__ unsigned short Vs[64 * 72];   // [px][ci] pad->72
    __shared__ unsigned short Ws[64 * 72];   // [o][ci]  pad->72
    __shared__ ushort4 cfA[9 * 64];          // fp16 {c00,c01,c10,c11}
    __shared__ int2    igA[9 * 64];          // {i00, dys | (dxs<<16)}

    int tid = threadIdx.x;
    int p0 = blockIdx.x * 64;
    int b = p0 / HWP;
    int rem0 = p0 % HWP;
    const unsigned short* xTb = xT + (size_t)b * HWP * 64;

    for (int e = tid; e < 9 * 64; e += 256) {
        int k = e / 64, px = e % 64;
        int p = p0 + px;
        float ys = ysA[(size_t)k * NPIX + p];
        float xs = xsA[(size_t)k * NPIX + p];
        float mk = bf2f(mA[(size_t)k * NPIX + p]);
        float y0f = floorf(ys), x0f = floorf(xs);
        int y0 = (int)y0f, x0 = (int)x0f;
        float wy = ys - y0f, wx = xs - x0f;
        float c00 = (1.f - wy) * (1.f - wx) * mk;
        float c01 = (1.f - wy) * wx * mk;
        float c10 = wy * (1.f - wx) * mk;
        float c11 = wy * wx * mk;
        bool vy0 = (y0 >= 0) && (y0 < HH);
        bool vy1 = (y0 + 1 >= 0) && (y0 + 1 < HH);
        bool vx0 = (x0 >= 0) && (x0 < WW);
        bool vx1 = (x0 + 1 >= 0) && (x0 + 1 < WW);
        c00 = (vy0 && vx0) ? c00 : 0.f;
        c01 = (vy0 && vx1) ? c01 : 0.f;
        c10 = (vy1 && vx0) ? c10 : 0.f;
        c11 = (vy1 && vx1) ? c11 : 0.f;
        int yc0 = min(max(y0, 0), HH - 1), yc1 = min(max(y0 + 1, 0), HH - 1);
        int xc0 = min(max(x0, 0), WW - 1), xc1 = min(max(x0 + 1, 0), WW - 1);
        int i00 = (yc0 * WW + xc0) * 64;
        int dys = (yc1 - yc0) * WW * 64;   // 0 or 20480
        int dxs = (xc1 - xc0) * 64;        // 0 or 64
        cfA[e] = make_ushort4(f2h(c00), f2h(c01), f2h(c10), f2h(c11));
        igA[e] = make_int2(i00, dys | (dxs << 16));
    }

    int lane = tid & 63;
    int wv = tid >> 6;
    int m0 = wv * 16;
    int lr = lane & 15;
    int lq = lane >> 4;

    f32x4 cini;
    cini[0] = cb[m0 + lq * 4 + 0];
    cini[1] = cb[m0 + lq * 4 + 1];
    cini[2] = cb[m0 + lq * 4 + 2];
    cini[3] = cb[m0 + lq * 4 + 3];
    f32x4 acc[4];
#pragma unroll
    for (int t = 0; t < 4; ++t) acc[t] = cini;

    int sgc = tid & 15;
    int sci0 = sgc * 4;
    int spx = tid >> 4;

    for (int k = 0; k < 9; ++k) {
        __syncthreads();
#pragma unroll
        for (int c = tid; c < 512; c += 256) {
            int o = c >> 3, g = c & 7;
            *(float4*)&Ws[o * 72 + g * 8] = ((const float4*)(cwT + (size_t)k * 4096))[c];
        }
#pragma unroll
        for (int q = 0; q < 4; ++q) {
            int px = q * 16 + spx;
            ushort4 ch = cfA[k * 64 + px];
            int2 ig = igA[k * 64 + px];
            float ccx = h2f(ch.x), ccy = h2f(ch.y), ccz = h2f(ch.z), ccw = h2f(ch.w);
            int i00 = ig.x + sci0;
            int dys = ig.y & 0xffff;
            int dxs = ig.y >> 16;
            int i01 = i00 + dxs;
            int i10 = i00 + dys;
            int i11 = i10 + dxs;
            ushort4 u00 = *(const ushort4*)&xTb[i00];
            ushort4 u01 = *(const ushort4*)&xTb[i01];
            ushort4 u10 = *(const ushort4*)&xTb[i10];
            ushort4 u11 = *(const ushort4*)&xTb[i11];
            float v0 = ccx * bf2f(u00.x) + ccy * bf2f(u01.x) + ccz * bf2f(u10.x) + ccw * bf2f(u11.x);
            float v1 = ccx * bf2f(u00.y) + ccy * bf2f(u01.y) + ccz * bf2f(u10.y) + ccw * bf2f(u11.y);
            float v2 = ccx * bf2f(u00.z) + ccy * bf2f(u01.z) + ccz * bf2f(u10.z) + ccw * bf2f(u11.z);
            float v3 = ccx * bf2f(u00.w) + ccy * bf2f(u01.w) + ccz * bf2f(u10.w) + ccw * bf2f(u11.w);
            uint2 r;
            r.x = pack2bf(v0, v1);
            r.y = pack2bf(v2, v3);
            *(uint2*)&Vs[px * 72 + sci0] = r;
        }
        __syncthreads();
        bf16x8 a0 = *(const bf16x8*)&Ws[(m0 + lr) * 72 + lq * 8];
        bf16x8 a1 = *(const bf16x8*)&Ws[(m0 + lr) * 72 + 32 + lq * 8];
#pragma unroll
        for (int t = 0; t < 4; ++t) {
            bf16x8 b0 = *(const bf16x8*)&Vs[(t * 16 + lr) * 72 + lq * 8];
            bf16x8 b1 = *(const bf16x8*)&Vs[(t * 16 + lr) * 72 + 32 + lq * 8];
            acc[t] = __builtin_amdgcn_mfma_f32_16x16x32_bf16(a0, b0, acc[t], 0, 0, 0);
            acc[t] = __builtin_amdgcn_mfma_f32_16x16x32_bf16(a1, b1, acc[t], 0, 0, 0);
        }
    }

#pragma unroll
    for (int t = 0; t < 4; ++t) {
#pragma unroll
        for (int r = 0; r < 4; ++r) {
            int o = m0 + lq * 4 + r;
            out[(size_t)(b * 64 + o) * HWP + rem0 + t * 16 + lr] = acc[t][r];
        }
    }
}

// ---------------------------------------------------------------------------
extern "C" void kernel_launch(void* const* d_in, const int* in_sizes, int n_in,
                              void* d_out, int out_size, void* d_ws, size_t ws_size,
                              hipStream_t stream) {
    const float* x   = (const float*)d_in[0];
    const float* sb  = (const float*)d_in[1];
    const float* gw1 = (const float*)d_in[2];
    const float* gb1 = (const float*)d_in[3];
    const float* gw2 = (const float*)d_in[4];
    const float* gb2 = (const float*)d_in[5];
    const float* lw1 = (const float*)d_in[6];
    const float* lb1 = (const float*)d_in[7];
    const float* lw2 = (const float*)d_in[8];
    const float* lb2 = (const float*)d_in[9];
    const float* fw1 = (const float*)d_in[10];
    const float* fb1 = (const float*)d_in[11];
    const float* fw2 = (const float*)d_in[12];
    const float* fb2 = (const float*)d_in[13];
    const float* mw  = (const float*)d_in[14];
    const float* mb  = (const float*)d_in[15];
    const float* cw  = (const float*)d_in[16];
    const float* cb  = (const float*)d_in[17];
    float* out = (float*)d_out;

    char* w = (char*)d_ws;
    float* gsum = (float*)w;                 w += 1152 * 4;
    unsigned short* cwT  = (unsigned short*)w; w += 36864 * 2;
    unsigned short* Wlm  = (unsigned short*)w; w += 27648 * 2;
    unsigned short* lw2T = (unsigned short*)w; w += 1024 * 2;
    unsigned short* Wf   = (unsigned short*)w; w += 9216 * 2;
    unsigned short* fw2A = (unsigned short*)w; w += 1024 * 2;
    unsigned short* mbuf = (unsigned short*)w; w += (size_t)9 * NPIX * 2;
    float* ysA = (float*)w;                  w += (size_t)9 * NPIX * 4;
    float* xsA = (float*)w;                  w += (size_t)9 * NPIX * 4;
    unsigned short* xT = (unsigned short*)w; w += (size_t)NPIX * 64 * 2;
    unsigned short* lT = (unsigned short*)w;

    k_prep<<<(PREP_N + 255) / 256, 256, 0, stream>>>(cw, lw1, mw, lw2, fw1, fw2,
                                                     cwT, Wlm, lw2T, Wf, fw2A);
    k_glob<<<1, 128, 0, stream>>>(sb, gw1, gb1, gw2, gb2, fw1, gsum);
    k_xT<<<NPIX / 64, 256, 0, stream>>>(x, xT);
    k_locmask<<<NPIX / 128, 256, 0, stream>>>(xT, Wlm, lw2T, lb1, lb2, mb, lT, mbuf);
    k_fuse<<<NPIX / 128, 256, 0, stream>>>(lT, gsum, Wf, fw2A, fb1, fb2, ysA, xsA);
    k_deform<<<NPIX / 64, 256, 0, stream>>>(xT, cwT, cb, ysA, xsA, mbuf, out);
}